// Round 4
// baseline (217.430 us; speedup 1.0000x reference)
//
#include <hip/hip_runtime.h>
#include <hip/hip_cooperative_groups.h>
#include <math.h>

namespace cg = cooperative_groups;

#define H 2048
#define V 50257
#define NTHR 256
#define LOGITS_BLOCKS 2048
#define FIN_BLOCKS 52

__device__ __forceinline__ float wave_reduce_sum(float v) {
#pragma unroll
    for (int off = 32; off > 0; off >>= 1)
        v += __shfl_down(v, off, 64);
    return v;
}

// ===========================================================================
// Fused cooperative kernel (grid-size agnostic).
// ===========================================================================
__global__ __launch_bounds__(NTHR, 4) void k_fused(
    const int* __restrict__ idx_p, const float* __restrict__ emb,
    const float* __restrict__ hid,
    const float* __restrict__ w_ih, const float* __restrict__ w_hh,
    const float* __restrict__ b_ih, const float* __restrict__ b_hh,
    const float* __restrict__ out_w, const float* __restrict__ out_b,
    float* __restrict__ out, float* __restrict__ gscratch,
    float2* __restrict__ partials) {
    cg::grid_group grid = cg::this_grid();
    __shared__ float xs[H];   // x = relu(emb[idx]); reused for hnew after A2
    __shared__ float hs[H];
    __shared__ float pm[4], ps[4];
    __shared__ float cs;
    const int tid = threadIdx.x, wid = tid >> 6, lane = tid & 63;
    const int nblk = gridDim.x;
    const int nw = nblk * 4;
    const int gw = blockIdx.x * 4 + wid;

    // ---- stage x = relu(emb[idx]) and h into LDS ----
    long idx = (long)idx_p[0];
    const float4* er = (const float4*)(emb + idx * (long)H);
    for (int i = tid; i < H / 4; i += NTHR) {
        float4 e = er[i];
        e.x = fmaxf(e.x, 0.f); e.y = fmaxf(e.y, 0.f);
        e.z = fmaxf(e.z, 0.f); e.w = fmaxf(e.w, 0.f);
        ((float4*)xs)[i] = e;
        ((float4*)hs)[i] = ((const float4*)hid)[i];
    }
    __syncthreads();

    // ---- phase A: 12288 GRU row-dots, grid-stride over waves ----
    for (int r = gw; r < 6 * H; r += nw) {
        const float* W   = (r < 3 * H) ? (w_ih + (size_t)r * H)
                                       : (w_hh + (size_t)(r - 3 * H) * H);
        const float* vec = (r < 3 * H) ? xs : hs;
        float acc = 0.f;
#pragma unroll
        for (int it = 0; it < 8; ++it) {
            float4 w4 = ((const float4*)W)[it * 64 + lane];
            float4 v4 = ((const float4*)vec)[it * 64 + lane];
            acc += w4.x * v4.x + w4.y * v4.y + w4.z * v4.z + w4.w * v4.w;
        }
        acc = wave_reduce_sum(acc);
        if (lane == 0) gscratch[r] = acc;
    }
    grid.sync();

    // ---- phase A2: every block computes the full hnew into xs ----
    const float4* gs4 = (const float4*)gscratch;
    const float4* bi4 = (const float4*)b_ih;
    const float4* bh4 = (const float4*)b_hh;
    for (int q = tid; q < H / 4; q += NTHR) {
        float4 ir = gs4[q],        iz = gs4[512 + q],  in_ = gs4[1024 + q];
        float4 hr = gs4[1536 + q], hz = gs4[2048 + q], hn  = gs4[2560 + q];
        float4 br = bi4[q],        bz = bi4[512 + q],  bn  = bi4[1024 + q];
        float4 cr = bh4[q],        cz = bh4[512 + q],  cn  = bh4[1024 + q];
        float4 h4 = ((const float4*)hs)[q];
        float irv[4] = {ir.x + br.x, ir.y + br.y, ir.z + br.z, ir.w + br.w};
        float izv[4] = {iz.x + bz.x, iz.y + bz.y, iz.z + bz.z, iz.w + bz.w};
        float inv[4] = {in_.x + bn.x, in_.y + bn.y, in_.z + bn.z, in_.w + bn.w};
        float hrv[4] = {hr.x + cr.x, hr.y + cr.y, hr.z + cr.z, hr.w + cr.w};
        float hzv[4] = {hz.x + cz.x, hz.y + cz.y, hz.z + cz.z, hz.w + cz.w};
        float hnv[4] = {hn.x + cn.x, hn.y + cn.y, hn.z + cn.z, hn.w + cn.w};
        float hov[4] = {h4.x, h4.y, h4.z, h4.w};
        float hv[4];
#pragma unroll
        for (int c = 0; c < 4; ++c) {
            float r = 1.f / (1.f + __expf(-(irv[c] + hrv[c])));
            float z = 1.f / (1.f + __expf(-(izv[c] + hzv[c])));
            float n = tanhf(inv[c] + r * hnv[c]);
            hv[c] = (1.f - z) * n + z * hov[c];
        }
        ((float4*)xs)[q] = make_float4(hv[0], hv[1], hv[2], hv[3]);
        if (blockIdx.x == 0) {
#pragma unroll
            for (int c = 0; c < 4; ++c) out[V + 4 * q + c] = hv[c];
        }
    }
    __syncthreads();

    // ---- phase B: vocab projection, 2-row ILP, logits -> out[0..V) ----
    float4 vreg[8];
#pragma unroll
    for (int it = 0; it < 8; ++it)
        vreg[it] = ((const float4*)xs)[it * 64 + lane];

    float m = -INFINITY, s = 0.f;
    for (int r0 = gw; r0 < V; r0 += 2 * nw) {
        int r1 = r0 + nw;
        if (r1 < V) {
            const float4* row0 = (const float4*)(out_w + (size_t)r0 * H);
            const float4* row1 = (const float4*)(out_w + (size_t)r1 * H);
            float a0 = 0.f, a1 = 0.f;
#pragma unroll
            for (int it = 0; it < 8; ++it) {
                float4 wa = row0[it * 64 + lane];
                float4 wb = row1[it * 64 + lane];
                a0 += wa.x * vreg[it].x + wa.y * vreg[it].y + wa.z * vreg[it].z + wa.w * vreg[it].w;
                a1 += wb.x * vreg[it].x + wb.y * vreg[it].y + wb.z * vreg[it].z + wb.w * vreg[it].w;
            }
            a0 = wave_reduce_sum(a0);
            a1 = wave_reduce_sum(a1);
            if (lane == 0) {
                float l0 = a0 + out_b[r0], l1 = a1 + out_b[r1];
                out[r0] = l0; out[r1] = l1;
                float M = fmaxf(m, fmaxf(l0, l1));
                s = s * __expf(m - M) + __expf(l0 - M) + __expf(l1 - M);
                m = M;
            }
        } else {
            const float4* row0 = (const float4*)(out_w + (size_t)r0 * H);
            float a0 = 0.f;
#pragma unroll
            for (int it = 0; it < 8; ++it) {
                float4 wa = row0[it * 64 + lane];
                a0 += wa.x * vreg[it].x + wa.y * vreg[it].y + wa.z * vreg[it].z + wa.w * vreg[it].w;
            }
            a0 = wave_reduce_sum(a0);
            if (lane == 0) {
                float l0 = a0 + out_b[r0];
                out[r0] = l0;
                float M = fmaxf(m, l0);
                s = s * __expf(m - M) + __expf(l0 - M);
                m = M;
            }
        }
    }
    if (lane == 0) { pm[wid] = m; ps[wid] = s; }
    __syncthreads();
    if (tid == 0) {
        float M = fmaxf(fmaxf(pm[0], pm[1]), fmaxf(pm[2], pm[3]));
        float S = ps[0] * __expf(pm[0] - M) + ps[1] * __expf(pm[1] - M) +
                  ps[2] * __expf(pm[2] - M) + ps[3] * __expf(pm[3] - M);
        partials[blockIdx.x] = make_float2(M, S);
    }
    grid.sync();

    // ---- phase C: merge partials (every block), in-place logp write ----
    {
        float mm = -INFINITY, ss = 0.f;
        for (int i = tid; i < nblk; i += NTHR) {
            float2 p = partials[i];
            float M = fmaxf(mm, p.x);
            ss = ss * __expf(mm - M) + p.y * __expf(p.x - M);
            mm = M;
        }
#pragma unroll
        for (int off = 32; off > 0; off >>= 1) {
            float om = __shfl_down(mm, off, 64);
            float os = __shfl_down(ss, off, 64);
            float M = fmaxf(mm, om);
            ss = ss * __expf(mm - M) + os * __expf(om - M);
            mm = M;
        }
        if (lane == 0) { pm[wid] = mm; ps[wid] = ss; }
        __syncthreads();
        if (tid == 0) {
            float M = fmaxf(fmaxf(pm[0], pm[1]), fmaxf(pm[2], pm[3]));
            float S = ps[0] * __expf(pm[0] - M) + ps[1] * __expf(pm[1] - M) +
                      ps[2] * __expf(pm[2] - M) + ps[3] * __expf(pm[3] - M);
            cs = M + logf(S);
        }
        __syncthreads();
    }
    float C = cs;
    for (int g = blockIdx.x * NTHR + tid; g < V / 4; g += nblk * NTHR) {
        float4 l4 = ((const float4*)out)[g];
        l4.x -= C; l4.y -= C; l4.z -= C; l4.w -= C;
        ((float4*)out)[g] = l4;
    }
    if (blockIdx.x == 0 && tid == 0) out[V - 1] -= C;
}

// ===========================================================================
// Fallback path (R2 kernels, known-good at 100 µs).
// ===========================================================================
__global__ __launch_bounds__(384) void k_gru_fb(
    const int* __restrict__ idx_p, const float* __restrict__ emb,
    const float* __restrict__ hid,
    const float* __restrict__ w_ih, const float* __restrict__ w_hh,
    const float* __restrict__ b_ih, const float* __restrict__ b_hh,
    float* __restrict__ hnew_ws, float* __restrict__ hnew_out) {
    __shared__ float xs[H];
    __shared__ float hs[H];
    __shared__ float partial[6][2];
    int tid = threadIdx.x;
    long idx = (long)idx_p[0];
    const float4* embrow = (const float4*)(emb + idx * (long)H);
    for (int i = tid; i < H / 4; i += 384) {
        float4 e = embrow[i];
        e.x = fmaxf(e.x, 0.f); e.y = fmaxf(e.y, 0.f);
        e.z = fmaxf(e.z, 0.f); e.w = fmaxf(e.w, 0.f);
        ((float4*)xs)[i] = e;
        ((float4*)hs)[i] = ((const float4*)hid)[i];
    }
    __syncthreads();
    int wid = tid >> 6, lane = tid & 63;
    int gate = wid % 3;
    const float* W   = (wid < 3) ? w_ih : w_hh;
    const float* vec = (wid < 3) ? xs : hs;
    int j0 = blockIdx.x, j1 = blockIdx.x + 1024;
    const float4* r0 = (const float4*)(W + ((size_t)gate * H + j0) * (size_t)H);
    const float4* r1 = (const float4*)(W + ((size_t)gate * H + j1) * (size_t)H);
    float4 vreg[8];
#pragma unroll
    for (int it = 0; it < 8; ++it) vreg[it] = ((const float4*)vec)[it * 64 + lane];
    float a0 = 0.f, a1 = 0.f;
#pragma unroll
    for (int it = 0; it < 8; ++it) {
        float4 wa = r0[it * 64 + lane];
        float4 wb = r1[it * 64 + lane];
        a0 += wa.x * vreg[it].x + wa.y * vreg[it].y + wa.z * vreg[it].z + wa.w * vreg[it].w;
        a1 += wb.x * vreg[it].x + wb.y * vreg[it].y + wb.z * vreg[it].z + wb.w * vreg[it].w;
    }
    a0 = wave_reduce_sum(a0);
    a1 = wave_reduce_sum(a1);
    if (lane == 0) { partial[wid][0] = a0; partial[wid][1] = a1; }
    __syncthreads();
    if (tid < 2) {
        int j = (tid == 0) ? j0 : j1;
        float i_r = partial[0][tid] + b_ih[j];
        float i_z = partial[1][tid] + b_ih[H + j];
        float i_n = partial[2][tid] + b_ih[2 * H + j];
        float h_r = partial[3][tid] + b_hh[j];
        float h_z = partial[4][tid] + b_hh[H + j];
        float h_n = partial[5][tid] + b_hh[2 * H + j];
        float r = 1.f / (1.f + expf(-(i_r + h_r)));
        float z = 1.f / (1.f + expf(-(i_z + h_z)));
        float n = tanhf(i_n + r * h_n);
        float hv = (1.f - z) * n + z * hs[j];
        hnew_ws[j] = hv;
        hnew_out[j] = hv;
    }
}

__global__ __launch_bounds__(256) void k_logits_fb(
    const float* __restrict__ out_w, const float* __restrict__ out_b,
    const float* __restrict__ hnew,
    float* __restrict__ logits, float2* __restrict__ partials) {
    __shared__ float hsm[H];
    __shared__ float pm[4], ps[4];
    int tid = threadIdx.x;
    for (int i = tid; i < H / 4; i += 256)
        ((float4*)hsm)[i] = ((const float4*)hnew)[i];
    __syncthreads();
    int wid = tid >> 6, lane = tid & 63;
    float4 vreg[8];
#pragma unroll
    for (int it = 0; it < 8; ++it) vreg[it] = ((const float4*)hsm)[it * 64 + lane];
    float m = -INFINITY, s = 0.f;
    for (int r = blockIdx.x * 4 + wid; r < V; r += LOGITS_BLOCKS * 4) {
        const float4* row = (const float4*)(out_w + (size_t)r * (size_t)H);
        float acc = 0.f;
#pragma unroll
        for (int it = 0; it < 8; ++it) {
            float4 w4 = row[it * 64 + lane];
            acc += w4.x * vreg[it].x + w4.y * vreg[it].y + w4.z * vreg[it].z + w4.w * vreg[it].w;
        }
        acc = wave_reduce_sum(acc);
        if (lane == 0) {
            float l = acc + out_b[r];
            logits[r] = l;
            float M = fmaxf(m, l);
            s = s * __expf(m - M) + __expf(l - M);
            m = M;
        }
    }
    if (lane == 0) { pm[wid] = m; ps[wid] = s; }
    __syncthreads();
    if (tid == 0) {
        float M = fmaxf(fmaxf(pm[0], pm[1]), fmaxf(pm[2], pm[3]));
        float S = ps[0] * __expf(pm[0] - M) + ps[1] * __expf(pm[1] - M) +
                  ps[2] * __expf(pm[2] - M) + ps[3] * __expf(pm[3] - M);
        partials[blockIdx.x] = make_float2(M, S);
    }
}

__global__ __launch_bounds__(256) void k_finalize_fb(
    const float* __restrict__ logits, const float2* __restrict__ partials,
    float* __restrict__ out) {
    __shared__ float pm[4], ps[4];
    __shared__ float cs;
    int tid = threadIdx.x;
    float m = -INFINITY, s = 0.f;
    for (int i = tid; i < LOGITS_BLOCKS; i += 256) {
        float2 p = partials[i];
        float M = fmaxf(m, p.x);
        s = s * __expf(m - M) + p.y * __expf(p.x - M);
        m = M;
    }
#pragma unroll
    for (int off = 32; off > 0; off >>= 1) {
        float om = __shfl_down(m, off, 64);
        float os = __shfl_down(s, off, 64);
        float M = fmaxf(m, om);
        s = s * __expf(m - M) + os * __expf(om - M);
        m = M;
    }
    int wid = tid >> 6, lane = tid & 63;
    if (lane == 0) { pm[wid] = m; ps[wid] = s; }
    __syncthreads();
    if (tid == 0) {
        float M = fmaxf(fmaxf(pm[0], pm[1]), fmaxf(pm[2], pm[3]));
        float S = ps[0] * __expf(pm[0] - M) + ps[1] * __expf(pm[1] - M) +
                  ps[2] * __expf(pm[2] - M) + ps[3] * __expf(pm[3] - M);
        cs = M + logf(S);
    }
    __syncthreads();
    float C = cs;
    int gid = blockIdx.x * 256 + tid;
    const int nf = V / 4;
    for (int i = gid; i < nf; i += FIN_BLOCKS * 256) {
        float4 l4 = ((const float4*)logits)[i];
        l4.x -= C; l4.y -= C; l4.z -= C; l4.w -= C;
        ((float4*)out)[i] = l4;
    }
    if (gid == 0) {
        for (int i = nf * 4; i < V; ++i) out[i] = logits[i] - C;
    }
}

extern "C" void kernel_launch(void* const* d_in, const int* in_sizes, int n_in,
                              void* d_out, int out_size, void* d_ws, size_t ws_size,
                              hipStream_t stream) {
    const int*   idx    = (const int*)d_in[0];
    const float* hidden = (const float*)d_in[1];
    const float* emb    = (const float*)d_in[2];
    const float* w_ih   = (const float*)d_in[3];
    const float* w_hh   = (const float*)d_in[4];
    const float* b_ih   = (const float*)d_in[5];
    const float* b_hh   = (const float*)d_in[6];
    const float* out_w  = (const float*)d_in[7];
    const float* out_b  = (const float*)d_in[8];

    float* out = (float*)d_out;                      // [V logp][H hnew]
    float* ws  = (float*)d_ws;
    float*  gscratch = ws;                           // 6*H floats (coop)
    float2* cpart    = (float2*)(ws + 6 * H);        // <=1024 float2 (coop)

    // --- cooperative sizing (host-only queries; capture-safe) ---
    int dev = 0;
    (void)hipGetDevice(&dev);
    int cus = 0;
    (void)hipDeviceGetAttribute(&cus, hipDeviceAttributeMultiprocessorCount, dev);
    int maxPerCU = 0;
    hipError_t oe = hipOccupancyMaxActiveBlocksPerMultiprocessor(
        &maxPerCU, (const void*)k_fused, NTHR, 0);

    int nblk = 0;
    if (oe == hipSuccess && cus > 0 && maxPerCU > 0) {
        nblk = maxPerCU * cus;
        if (nblk > 1024) nblk = 1024;
    }

    if (nblk >= 128) {
        void* args[] = {
            (void*)&idx, (void*)&emb, (void*)&hidden,
            (void*)&w_ih, (void*)&w_hh, (void*)&b_ih, (void*)&b_hh,
            (void*)&out_w, (void*)&out_b,
            (void*)&out, (void*)&gscratch, (void*)&cpart,
        };
        hipError_t le = hipLaunchCooperativeKernel(
            (const void*)k_fused, dim3(nblk), dim3(NTHR), args, 0, stream);
        if (le == hipSuccess) return;
    }

    // --- fallback: known-good 3-kernel path ---
    float*  hnew     = ws;
    float*  logits   = ws + H;
    float2* partials = (float2*)(ws + H + ((V + 1) & ~1));
    k_gru_fb<<<1024, 384, 0, stream>>>(idx, emb, hidden, w_ih, w_hh, b_ih, b_hh,
                                       hnew, out + V);
    k_logits_fb<<<LOGITS_BLOCKS, 256, 0, stream>>>(out_w, out_b, hnew, logits,
                                                   partials);
    k_finalize_fb<<<FIN_BLOCKS, 256, 0, stream>>>(logits, partials, out);
}

// Round 5
// 100.902 us; speedup vs baseline: 2.1549x; 2.1549x over previous
//
#include <hip/hip_runtime.h>
#include <math.h>

#define H 2048
#define V 50257

#define LOGITS_BLOCKS 2048
#define LOGITS_WAVES (LOGITS_BLOCKS * 4)   // 8192 waves
#define FIN_BLOCKS 52

__device__ __forceinline__ float wave_reduce_sum(float v) {
#pragma unroll
    for (int off = 32; off > 0; off >>= 1)
        v += __shfl_down(v, off, 64);
    return v;
}

// ---------------------------------------------------------------------------
// GRU step, embed fused. 1024 blocks; block b handles hidden elems b and b+1024.
// 6 waves: waves 0-2 dot w_ih gate rows with x=relu(emb[idx]); waves 3-5 dot
// w_hh gate rows with h. 2 rows per wave -> 16 dwordx4 loads in flight.
// ---------------------------------------------------------------------------
__global__ __launch_bounds__(384) void k_gru(
    const int* __restrict__ idx_p, const float* __restrict__ emb,
    const float* __restrict__ hid,
    const float* __restrict__ w_ih, const float* __restrict__ w_hh,
    const float* __restrict__ b_ih, const float* __restrict__ b_hh,
    float* __restrict__ hnew_ws, float* __restrict__ hnew_out) {
    __shared__ float xs[H];
    __shared__ float hs[H];
    __shared__ float partial[6][2];
    int tid = threadIdx.x;

    long idx = (long)idx_p[0];
    const float4* embrow = (const float4*)(emb + idx * (long)H);
    for (int i = tid; i < H / 4; i += 384) {
        float4 e = embrow[i];
        e.x = fmaxf(e.x, 0.f); e.y = fmaxf(e.y, 0.f);
        e.z = fmaxf(e.z, 0.f); e.w = fmaxf(e.w, 0.f);
        ((float4*)xs)[i] = e;
        ((float4*)hs)[i] = ((const float4*)hid)[i];
    }
    __syncthreads();

    int wid = tid >> 6, lane = tid & 63;
    int gate = wid % 3;
    const float* W   = (wid < 3) ? w_ih : w_hh;
    const float* vec = (wid < 3) ? xs : hs;
    int j0 = blockIdx.x, j1 = blockIdx.x + 1024;
    const float4* r0 = (const float4*)(W + ((size_t)gate * H + j0) * (size_t)H);
    const float4* r1 = (const float4*)(W + ((size_t)gate * H + j1) * (size_t)H);

    float4 vreg[8];
#pragma unroll
    for (int it = 0; it < 8; ++it)
        vreg[it] = ((const float4*)vec)[it * 64 + lane];

    float a0 = 0.f, a1 = 0.f;
#pragma unroll
    for (int it = 0; it < 8; ++it) {
        float4 wa = r0[it * 64 + lane];
        float4 wb = r1[it * 64 + lane];
        a0 += wa.x * vreg[it].x + wa.y * vreg[it].y + wa.z * vreg[it].z + wa.w * vreg[it].w;
        a1 += wb.x * vreg[it].x + wb.y * vreg[it].y + wb.z * vreg[it].z + wb.w * vreg[it].w;
    }
    a0 = wave_reduce_sum(a0);
    a1 = wave_reduce_sum(a1);
    if (lane == 0) { partial[wid][0] = a0; partial[wid][1] = a1; }
    __syncthreads();

    if (tid < 2) {
        int j = (tid == 0) ? j0 : j1;
        float i_r = partial[0][tid] + b_ih[j];
        float i_z = partial[1][tid] + b_ih[H + j];
        float i_n = partial[2][tid] + b_ih[2 * H + j];
        float h_r = partial[3][tid] + b_hh[j];
        float h_z = partial[4][tid] + b_hh[H + j];
        float h_n = partial[5][tid] + b_hh[2 * H + j];
        float r = 1.f / (1.f + expf(-(i_r + h_r)));
        float z = 1.f / (1.f + expf(-(i_z + h_z)));
        float n = tanhf(i_n + r * h_n);
        float hv = (1.f - z) * n + z * hs[j];
        hnew_ws[j] = hv;
        hnew_out[j] = hv;
    }
}

// ---------------------------------------------------------------------------
// Vocab projection. 2048 blocks x 4 waves; each wave does 3 pairs of rows
// (r, r+8192) -> 16 dwordx4 in flight; h_new pinned in 32 VGPRs.
// Raw logits written directly to out[0..V). Per-block online (m, sumexp).
// ---------------------------------------------------------------------------
__global__ __launch_bounds__(256, 4) void k_logits(
    const float* __restrict__ out_w, const float* __restrict__ out_b,
    const float* __restrict__ hnew,
    float* __restrict__ out, float2* __restrict__ partials) {
    __shared__ float hsm[H];
    __shared__ float pm[4], ps[4];
    int tid = threadIdx.x;
    for (int i = tid; i < H / 4; i += 256)
        ((float4*)hsm)[i] = ((const float4*)hnew)[i];
    __syncthreads();

    int wid = tid >> 6, lane = tid & 63;
    const int gw = blockIdx.x * 4 + wid;   // 0..8191
    float4 vreg[8];
#pragma unroll
    for (int it = 0; it < 8; ++it)
        vreg[it] = ((const float4*)hsm)[it * 64 + lane];

    float m = -INFINITY, s = 0.f;
#pragma unroll 1
    for (int t = 0; t < 3; ++t) {
        int r0 = gw + t * 16384;
        int r1 = r0 + 8192;
        const float4* row0 = (const float4*)(out_w + (size_t)r0 * H);
        const float4* row1 = (const float4*)(out_w + (size_t)r1 * H);
        float a0 = 0.f, a1 = 0.f;
#pragma unroll
        for (int it = 0; it < 8; ++it) {
            float4 wa = row0[it * 64 + lane];
            float4 wb = row1[it * 64 + lane];
            a0 += wa.x * vreg[it].x + wa.y * vreg[it].y + wa.z * vreg[it].z + wa.w * vreg[it].w;
            a1 += wb.x * vreg[it].x + wb.y * vreg[it].y + wb.z * vreg[it].z + wb.w * vreg[it].w;
        }
        a0 = wave_reduce_sum(a0);
        a1 = wave_reduce_sum(a1);
        if (lane == 0) {
            float l0 = a0 + out_b[r0], l1 = a1 + out_b[r1];
            out[r0] = l0; out[r1] = l1;
            float M = fmaxf(m, fmaxf(l0, l1));
            s = s * __expf(m - M) + __expf(l0 - M) + __expf(l1 - M);
            m = M;
        }
    }
    if (gw < V - 49152) {   // 1105 tail rows
        int r = 49152 + gw;
        const float4* row = (const float4*)(out_w + (size_t)r * H);
        float a0 = 0.f;
#pragma unroll
        for (int it = 0; it < 8; ++it) {
            float4 wa = row[it * 64 + lane];
            a0 += wa.x * vreg[it].x + wa.y * vreg[it].y + wa.z * vreg[it].z + wa.w * vreg[it].w;
        }
        a0 = wave_reduce_sum(a0);
        if (lane == 0) {
            float l = a0 + out_b[r];
            out[r] = l;
            float M = fmaxf(m, l);
            s = s * __expf(m - M) + __expf(l - M);
            m = M;
        }
    }
    if (lane == 0) { pm[wid] = m; ps[wid] = s; }
    __syncthreads();
    if (tid == 0) {
        float M = fmaxf(fmaxf(pm[0], pm[1]), fmaxf(pm[2], pm[3]));
        float S = ps[0] * __expf(pm[0] - M) + ps[1] * __expf(pm[1] - M) +
                  ps[2] * __expf(pm[2] - M) + ps[3] * __expf(pm[3] - M);
        partials[blockIdx.x] = make_float2(M, S);
    }
}

// ---------------------------------------------------------------------------
// Merge the 2048 block partials (each block redundantly; 16 KB, L2-hot),
// then out[i] -= C in place with float4 accesses.
// ---------------------------------------------------------------------------
__global__ __launch_bounds__(256) void k_finalize(
    const float2* __restrict__ partials, float* __restrict__ out) {
    __shared__ float pm[4], ps[4];
    __shared__ float cs;
    int tid = threadIdx.x;

    float m = -INFINITY, s = 0.f;
    for (int i = tid; i < LOGITS_BLOCKS; i += 256) {
        float2 p = partials[i];
        float M = fmaxf(m, p.x);
        s = s * __expf(m - M) + p.y * __expf(p.x - M);
        m = M;
    }
#pragma unroll
    for (int off = 32; off > 0; off >>= 1) {
        float om = __shfl_down(m, off, 64);
        float os = __shfl_down(s, off, 64);
        float M = fmaxf(m, om);
        s = s * __expf(m - M) + os * __expf(om - M);
        m = M;
    }
    int wid = tid >> 6, lane = tid & 63;
    if (lane == 0) { pm[wid] = m; ps[wid] = s; }
    __syncthreads();
    if (tid == 0) {
        float M = fmaxf(fmaxf(pm[0], pm[1]), fmaxf(pm[2], pm[3]));
        float S = ps[0] * __expf(pm[0] - M) + ps[1] * __expf(pm[1] - M) +
                  ps[2] * __expf(pm[2] - M) + ps[3] * __expf(pm[3] - M);
        cs = M + logf(S);
    }
    __syncthreads();
    float C = cs;

    int gid = blockIdx.x * 256 + tid;
    const int nf = V / 4;   // 12564 float4s cover 0..50255
    for (int i = gid; i < nf; i += FIN_BLOCKS * 256) {
        float4 l4 = ((const float4*)out)[i];
        l4.x -= C; l4.y -= C; l4.z -= C; l4.w -= C;
        ((float4*)out)[i] = l4;
    }
    if (gid == 0) out[V - 1] -= C;
}

extern "C" void kernel_launch(void* const* d_in, const int* in_sizes, int n_in,
                              void* d_out, int out_size, void* d_ws, size_t ws_size,
                              hipStream_t stream) {
    const int*   idx    = (const int*)d_in[0];
    const float* hidden = (const float*)d_in[1];
    const float* emb    = (const float*)d_in[2];
    const float* w_ih   = (const float*)d_in[3];
    const float* w_hh   = (const float*)d_in[4];
    const float* b_ih   = (const float*)d_in[5];
    const float* b_hh   = (const float*)d_in[6];
    const float* out_w  = (const float*)d_in[7];
    const float* out_b  = (const float*)d_in[8];

    float* out = (float*)d_out;                  // [V logp][H hnew]
    float* ws  = (float*)d_ws;
    float*  hnew     = ws;                       // H floats
    float2* partials = (float2*)(ws + H);        // LOGITS_BLOCKS float2

    k_gru<<<1024, 384, 0, stream>>>(idx, emb, hidden, w_ih, w_hh, b_ih, b_hh,
                                    hnew, out + V);
    k_logits<<<LOGITS_BLOCKS, 256, 0, stream>>>(out_w, out_b, hnew, out, partials);
    k_finalize<<<FIN_BLOCKS, 256, 0, stream>>>(partials, out);
}